// Round 4
// baseline (170.791 us; speedup 1.0000x reference)
//
#include <hip/hip_runtime.h>
#include <math.h>

#define N_NODES 50000
#define IN_CH 256
#define N_REL 5
#define N_EDGES 800000
#define N_GLOB 20000   // LAST_GLOBALS - LAST_SENSES
#define N_SENSE 25000
#define N_OUT 45000
#define MAX_MATCH 256      // E[matches]=16; 256 is astronomically safe
#define LOGIT_BLOCKS 2048
#define NWAVES (LOGIT_BLOCKS * 4)   // 8192 waves, ~5.5 rows each
#define N_OUT4 (N_OUT / 4)          // 11250 float4s; 5000 = global/sense split
#define N_GLOB4 (N_GLOB / 4)

// ---------------- workspace layout (floats from base) ----------------
// x1acc : [0, 256)      atomic accumulator for pre-relu x1 (memset 0)
// ip    : ints at float offset 256: [0]=match count, [1..5]=per-rel cnt,
//         [8..264)=src, [264..520)=type   (ip[0..7] memset 0)
// raw   : [1024, 46024) unnormalized logits (16B-aligned at float 1024)
// memset covers floats [0, 264) = 1056 bytes.

__device__ __forceinline__ void record_edge(const int* ei, const int* et,
                                            int* ip, int e) {
    int t = et[e];
    int p = atomicAdd(&ip[0], 1);
    if (p < MAX_MATCH) {
        ip[8 + p] = ei[e];               // src
        ip[8 + MAX_MATCH + p] = t;       // type
    }
    atomicAdd(&ip[1 + t], 1);
}

// collect edges with dst == 0 (int4-vectorized dst scan)
__global__ void k_scan(const int* __restrict__ ei,
                       const int* __restrict__ et,
                       int* __restrict__ ip) {
    int e4 = blockIdx.x * 256 + threadIdx.x;
    if (e4 * 4 >= N_EDGES) return;
    int4 d = ((const int4*)(ei + N_EDGES))[e4];
    int e = e4 * 4;
    if (d.x == 0) record_edge(ei, et, ip, e);
    if (d.y == 0) record_edge(ei, et, ip, e + 1);
    if (d.z == 0) record_edge(ei, et, ip, e + 2);
    if (d.w == 0) record_edge(ei, et, ip, e + 3);
}

// 24 blocks = 6 matrices (5 basis + root) x 4 row-slices of 64.
// Slice trick: rows d0..d0+63 of the matvec need only u[d0..d0+63],
// so the per-block u-gather is a 4KB slice of the matched x rows.
// x1acc[f] += sum_d u[d] * M[d][f]   (atomic across 24 blocks)
__global__ void k_x1(const float* __restrict__ x,
                     const float* __restrict__ comp,
                     const float* __restrict__ basis,
                     const float* __restrict__ root,
                     const float* __restrict__ bias,
                     const int* __restrict__ ip,
                     float* __restrict__ x1acc) {
    __shared__ float u[64];
    int tid = threadIdx.x;
    int mat = blockIdx.x >> 2;           // 0..5
    int d0 = (blockIdx.x & 3) * 64;
    if (tid < 64) {
        if (mat < 5) {
            int m = ip[0]; if (m > MAX_MATCH) m = MAX_MATCH;
            float acc = 0.f;
            for (int j = 0; j < m; ++j) {
                int s = ip[8 + j];
                int t = ip[8 + MAX_MATCH + j];
                float scale = comp[t * N_REL + mat] /
                              fmaxf((float)ip[1 + t], 1.0f);
                acc += scale * x[(size_t)s * IN_CH + d0 + tid];
            }
            u[tid] = acc;
        } else {
            u[tid] = x[d0 + tid];        // root operand: x[0] row slice
        }
    }
    __syncthreads();
    const float* M = ((mat < 5) ? (basis + (size_t)mat * IN_CH * IN_CH)
                                : root) + (size_t)d0 * IN_CH;
    float acc = 0.f;
#pragma unroll 16
    for (int d = 0; d < 64; ++d) acc += u[d] * M[d * IN_CH + tid];
    if (mat == 5 && d0 == 0) acc += bias[tid];
    atomicAdd(&x1acc[tid], acc);
}

// grid-stride waves; no LDS, x1 float4 straight from L2 with relu in-register.
// Writes RAW logits to ws (normalization done by k_statsfinal into d_out).
__global__ void k_logits(const float* __restrict__ Wg,
                         const float* __restrict__ bg,
                         const float* __restrict__ Ws,
                         const float* __restrict__ bs,
                         const float* __restrict__ x1acc,
                         float* __restrict__ raw) {
    int tid = threadIdx.x, lane = tid & 63;
    int gw = blockIdx.x * 4 + (tid >> 6);
    float4 xv = ((const float4*)x1acc)[lane];
    xv.x = fmaxf(xv.x, 0.f); xv.y = fmaxf(xv.y, 0.f);
    xv.z = fmaxf(xv.z, 0.f); xv.w = fmaxf(xv.w, 0.f);
    for (int row = gw; row < N_OUT; row += NWAVES) {
        const float4* wr;
        float b;
        if (row < N_GLOB) {
            wr = (const float4*)(Wg + (size_t)row * IN_CH);
            b = bg[row];
        } else {
            int r2 = row - N_GLOB;
            wr = (const float4*)(Ws + (size_t)r2 * IN_CH);
            b = bs[r2];
        }
        float4 wv = wr[lane];
        float s = wv.x * xv.x + wv.y * xv.y + wv.z * xv.z + wv.w * xv.w;
#pragma unroll
        for (int off = 32; off > 0; off >>= 1) s += __shfl_down(s, off);
        if (lane == 0) raw[row] = s + b;
    }
}

// 44 blocks x 256 thr. Each block redundantly computes both segments'
// (max, logZ) from raw (L2-hot, 2 float4 passes), then writes its own
// normalized float4s to d_out. raw/out split -> no cross-block race.
__global__ void k_statsfinal(const float* __restrict__ raw,
                             float* __restrict__ out) {
    __shared__ float r1[256], r2[256];
    int tid = threadIdx.x;
    const float4* o4 = (const float4*)raw;
    float mg = -3.4e38f, ms = -3.4e38f;
    for (int i = tid; i < N_OUT4; i += 256) {
        float4 v = o4[i];
        float m4 = fmaxf(fmaxf(v.x, v.y), fmaxf(v.z, v.w));
        if (i < N_GLOB4) mg = fmaxf(mg, m4); else ms = fmaxf(ms, m4);
    }
    r1[tid] = mg; r2[tid] = ms; __syncthreads();
    for (int h = 128; h > 0; h >>= 1) {
        if (tid < h) {
            r1[tid] = fmaxf(r1[tid], r1[tid + h]);
            r2[tid] = fmaxf(r2[tid], r2[tid + h]);
        }
        __syncthreads();
    }
    mg = r1[0]; ms = r2[0]; __syncthreads();
    float sg = 0.f, ss = 0.f;
    for (int i = tid; i < N_OUT4; i += 256) {
        float4 v = o4[i];
        if (i < N_GLOB4)
            sg += expf(v.x - mg) + expf(v.y - mg) + expf(v.z - mg) + expf(v.w - mg);
        else
            ss += expf(v.x - ms) + expf(v.y - ms) + expf(v.z - ms) + expf(v.w - ms);
    }
    r1[tid] = sg; r2[tid] = ss; __syncthreads();
    for (int h = 128; h > 0; h >>= 1) {
        if (tid < h) { r1[tid] += r1[tid + h]; r2[tid] += r2[tid + h]; }
        __syncthreads();
    }
    float zg = mg + logf(r1[0]);
    float zs = ms + logf(r2[0]);
    int i = blockIdx.x * 256 + tid;
    if (i < N_OUT4) {
        float4 v = o4[i];
        float z = (i < N_GLOB4) ? zg : zs;
        v.x -= z; v.y -= z; v.z -= z; v.w -= z;
        ((float4*)out)[i] = v;
    }
}

extern "C" void kernel_launch(void* const* d_in, const int* in_sizes, int n_in,
                              void* d_out, int out_size, void* d_ws, size_t ws_size,
                              hipStream_t stream) {
    const float* x     = (const float*)d_in[0];
    const int*   ei    = (const int*)  d_in[1];
    const int*   et    = (const int*)  d_in[2];
    const float* comp  = (const float*)d_in[3];
    const float* basis = (const float*)d_in[4];
    const float* root  = (const float*)d_in[5];
    const float* bias  = (const float*)d_in[6];
    const float* Wg    = (const float*)d_in[7];
    const float* bg    = (const float*)d_in[8];
    const float* Wsn   = (const float*)d_in[9];
    const float* bs    = (const float*)d_in[10];
    float* out = (float*)d_out;

    float* base  = (float*)d_ws;
    float* x1acc = base;                 // 256
    int*   ip    = (int*)(base + 256);   // 8 + 2*MAX_MATCH ints
    float* raw   = base + 1024;          // 45000, 16B-aligned

    hipMemsetAsync(d_ws, 0, 1056, stream);   // x1acc + ip[0..7]
    k_scan      <<<(N_EDGES / 4 + 255) / 256, 256, 0, stream>>>(ei, et, ip);
    k_x1        <<<24, 256, 0, stream>>>(x, comp, basis, root, bias, ip, x1acc);
    k_logits    <<<LOGIT_BLOCKS, 256, 0, stream>>>(Wg, bg, Wsn, bs, x1acc, raw);
    k_statsfinal<<<(N_OUT4 + 255) / 256, 256, 0, stream>>>(raw, out);
}